// Round 15
// baseline (662.983 us; speedup 1.0000x reference)
//
#include <hip/hip_runtime.h>
#include <hip/hip_bf16.h>

// Problem constants
#define BDIM 1024
#define ROI 200
#define DIN 200
#define NSUB 8
#define NROWS (BDIM * ROI)           // 204800
#define XELEMS ((size_t)NROWS * 200) // 40,960,000
#define PLPAD 32                     // tail pad (shorts) per plane for k-overrun
#define PLSZ (XELEMS + PLPAD)        // shorts per bf16 plane
#define G13 (13 * 7 * 64)            // W granules, full-width fragment-major

typedef __attribute__((ext_vector_type(8))) short short8;
typedef __attribute__((ext_vector_type(4))) float f32x4;

__device__ __constant__ float d_invcnt[8] = {
    1.f/41.f, 1.f/29.f, 1.f/21.f, 1.f/19.f, 1.f/20.f, 1.f/7.f, 1.f/21.f, 1.f/42.f};

__device__ inline unsigned short f2bf_rn(float x) {
  unsigned u = __float_as_uint(x);
  return (unsigned short)((u + 0x7FFFu + ((u >> 16) & 1u)) >> 16);
}
__device__ constexpr int seg_of_c(int r) {
  return (r < 41) ? 0 : (r < 70) ? 1 : (r < 91) ? 2 : (r < 110) ? 3
       : (r < 130) ? 4 : (r < 137) ? 5 : (r < 158) ? 6 : 7;
}

// async global->LDS, 16B per lane; LDS dest = wave-uniform base + lane*16
__device__ inline void gload_lds16(const unsigned short* src, unsigned short* dst) {
  __builtin_amdgcn_global_load_lds(
      (const __attribute__((address_space(1))) void*)src,
      (__attribute__((address_space(3))) void*)dst, 16, 0, 0);
}

// Issue one wave's 16-row x 32-granule A tile (8 async wave-loads).
// LDS layout linear in slot s; slot s holds granule(row=s>>5, c=(s&31)^(row&7))
// -> read side uses the same XOR, giving conflict-free ds_read_b128.
__device__ inline void issue_a64(const unsigned short* __restrict__ A,
                                 int grow0, int lane, unsigned short* buf) {
  #pragma unroll
  for (int j = 0; j < 8; ++j) {
    int s = j * 64 + lane;
    int rr = s >> 5;
    int c = (s & 31) ^ (rr & 7);
    if (c > 27) c = 0;  // pad slot, never read
    gload_lds16(A + (size_t)(grow0 + rr) * 200 + c * 8, buf + (size_t)j * 64 * 8);
  }
}

// A-burst: whole K strip (7 granules) for two 16-row fragments (for w34)
__device__ inline void aburst7(const unsigned short* pA, const unsigned short* pB,
                               short8 (&aA)[7], short8 (&aB)[7]) {
  #pragma unroll
  for (int i = 0; i < 7; ++i) {
    aA[i] = *(const short8*)(pA + i * 32);
    aB[i] = *(const short8*)(pB + i * 32);
  }
}

// rs_intra: one wave per row, 4 rows per block
__global__ __launch_bounds__(256) void rowsum4_k(const float* __restrict__ in,
                                                 float* __restrict__ out) {
  int row = blockIdx.x * 4 + (threadIdx.x >> 6);
  int lane = threadIdx.x & 63;
  const float* p = in + (size_t)row * 200;
  float v = p[lane] + p[lane + 64] + p[lane + 128];
  if (lane < 8) v += p[lane + 192];
  #pragma unroll
  for (int off = 32; off > 0; off >>= 1) v += __shfl_down(v, off);
  if (lane == 0) out[row] = v;
}

__global__ __launch_bounds__(256) void intersum_k(const float* __restrict__ in,
                                                  float* __restrict__ out) {
  int i = blockIdx.x * blockDim.x + threadIdx.x;
  if (i >= BDIM * NSUB) return;
  const float* p = in + (size_t)i * 8;
  float v = 0.f;
  #pragma unroll
  for (int c = 0; c < 8; ++c) v += p[c];
  out[i] = v;
}

// Fused seg_mean + block_combine (+ optional BN fold), r-major full unroll.
template<int INPL, int BN>
__global__ __launch_bounds__(128) void seg_combine_bf_k(
    const float* __restrict__ xf, const unsigned short* __restrict__ xp,
    const float* __restrict__ rsI, const float* __restrict__ rsP,
    const float* __restrict__ ss, unsigned short* __restrict__ yp) {
  int b = blockIdx.x;
  int t = threadIdx.x;
  if (t >= 100) return;
  int c0 = 2 * t;
  size_t base = (size_t)b * 40000 + c0;
  float sc0 = 1.f, sh0 = 0.f, sc1 = 1.f, sh1 = 0.f;
  if (BN) { sc0 = ss[c0]; sh0 = ss[200 + c0]; sc1 = ss[c0 + 1]; sh1 = ss[200 + c0 + 1]; }
  float a0[8] = {0,0,0,0,0,0,0,0};
  float a1[8] = {0,0,0,0,0,0,0,0};
  #pragma unroll
  for (int r = 0; r < 200; ++r) {
    size_t idx = base + (size_t)r * 200;
    float v0, v1;
    if (INPL) {
      unsigned u = *(const unsigned*)(xp + idx);
      v0 = __uint_as_float(u << 16);
      v1 = __uint_as_float(u & 0xFFFF0000u);
    } else {
      float2 fv = *(const float2*)(xf + idx);
      v0 = fv.x; v1 = fv.y;
    }
    int s = seg_of_c(r);
    a0[s] += v0; a1[s] += v1;
  }
  float pr0[8], pr1[8];
  #pragma unroll
  for (int s = 0; s < 8; ++s) {
    float m0 = a0[s] * d_invcnt[s];
    float m1 = a1[s] * d_invcnt[s];
    if (BN) { m0 = m0 * sc0 + sh0; m1 = m1 * sc1 + sh1; }
    float rp = rsP[b * 8 + s];
    pr0[s] = rp * m0; pr1[s] = rp * m1;
  }
  const float* rsIb = rsI + b * 200;
  #pragma unroll
  for (int r = 0; r < 200; ++r) {
    size_t idx = base + (size_t)r * 200;
    float v0, v1;
    if (INPL) {
      unsigned u = *(const unsigned*)(xp + idx);
      v0 = __uint_as_float(u << 16);
      v1 = __uint_as_float(u & 0xFFFF0000u);
    } else {
      float2 fv = *(const float2*)(xf + idx);
      v0 = fv.x; v1 = fv.y;
    }
    if (BN) { v0 = v0 * sc0 + sh0; v1 = v1 * sc1 + sh1; }
    int s = seg_of_c(r);
    float ri = rsIb[r];
    float y0 = 0.5f * (ri * v0 + pr0[s]);
    float y1 = 0.5f * (ri * v1 + pr1[s]);
    unsigned o = (unsigned)f2bf_rn(y0) | ((unsigned)f2bf_rn(y1) << 16);
    *(unsigned*)(yp + idx) = o;
  }
}

// Weight preconversion into per-colblock fragment-major granule layout.
__global__ __launch_bounds__(256) void wconv3_k(const float* __restrict__ W, int K, int N,
                                                int NFRAG, int NB, int KSTEPS,
                                                unsigned short* __restrict__ dst) {
  int total = NB * KSTEPS * NFRAG * 64 * 8;
  int idx = blockIdx.x * 256 + threadIdx.x;
  if (idx >= total) return;
  int j = idx & 7;
  int lane = (idx >> 3) & 63;
  int rest = idx >> 9;
  int frag = rest % NFRAG;
  int rest2 = rest / NFRAG;
  int ks = rest2 % KSTEPS;
  int cb = rest2 / KSTEPS;
  int k = ks * 32 + ((lane >> 4) << 3) + j;
  int col = cb * NFRAG * 16 + frag * 16 + (lane & 15);
  float v = (k < K && col < N) ? W[(size_t)k * N + col] : 0.f;
  dst[idx] = f2bf_rn(v);
}

// Barrier-free wave-local async-LDS GEMM (full-width NFRAG=13, A read once).
// 256 thr = 4 waves x 16 rows = 64-row tiles; grid 256 (1 block/CU);
// tiles t = bid + 256*i. Per wave: 2-buffer ping-pong of its own 16-row
// A tile, issued via global_load_lds with counted s_waitcnt vmcnt(8) —
// NO barriers in the main loop (loads stay in flight across tiles).
template<int ACT, int STATS>
__global__ __launch_bounds__(256, 1) void gemm_bf2_k(
    const unsigned short* __restrict__ A, const unsigned short* __restrict__ Wf,
    const float* __restrict__ bias, unsigned short* __restrict__ Cp,
    float* __restrict__ stats) {
  __shared__ unsigned short wlds[G13 * 8];        // 93,184 B
  __shared__ unsigned short abuf[4][2][4096];     // 65,536 B
  __shared__ float s_sum[208];
  __shared__ float s_sq[208];
  int tid = threadIdx.x;
  int lane = tid & 63;
  int wid = tid >> 6;

  for (int g0 = wid * 64; g0 < G13; g0 += 256)
    gload_lds16(Wf + (size_t)(g0 + lane) * 8, &wlds[(size_t)g0 * 8]);
  if (STATS && tid < 208) { s_sum[tid] = 0.f; s_sq[tid] = 0.f; }

  int bid = blockIdx.x;
  int row = lane & 15;
  int laneg = lane >> 4;
  int rxor = row & 7;

  issue_a64(A, bid * 64 + wid * 16, lane, &abuf[wid][0][0]);
  if (bid + 256 < 3200)
    issue_a64(A, (bid + 256) * 64 + wid * 16, lane, &abuf[wid][1][0]);
  __syncthreads();  // W + first tiles resident (full drain, once)

  for (int i = 0; ; ++i) {
    int tile = bid + i * 256;
    if (tile >= 3200) break;
    if (i > 0) {
      asm volatile("s_waitcnt vmcnt(8)" ::: "memory");
      __builtin_amdgcn_sched_barrier(0);
    }
    const unsigned short* ab = &abuf[wid][i & 1][0];
    f32x4 acc[13];
    #pragma unroll
    for (int f = 0; f < 13; ++f) acc[f] = 0.0f;
    #pragma unroll
    for (int ks = 0; ks < 7; ++ks) {
      int cs = (ks * 4 + laneg) ^ rxor;
      short8 av = *(const short8*)&ab[(size_t)(row * 32 + cs) * 8];
      const short8* wp = (const short8*)wlds + (size_t)(ks * 13) * 64 + lane;
      #pragma unroll
      for (int f = 0; f < 13; ++f) {
        short8 wv = wp[(size_t)f * 64];
        acc[f] = __builtin_amdgcn_mfma_f32_16x16x32_bf16(av, wv, acc[f], 0, 0, 0);
      }
    }
    int row0 = tile * 64 + wid * 16 + laneg * 4;
    #pragma unroll
    for (int f = 0; f < 13; ++f) {
      int col = f * 16 + row;
      if (col < 200) {
        float b = bias[col];
        float ls = 0.f, lq = 0.f;
        #pragma unroll
        for (int r = 0; r < 4; ++r) {
          float v = acc[f][r] + b;
          if (ACT) v = (v >= 0.f) ? v : 0.2f * v;
          Cp[(size_t)(row0 + r) * 200 + col] = f2bf_rn(v);
          if (STATS) { ls += v; lq += v * v; }
        }
        if (STATS) {
          atomicAdd(&s_sum[col], ls);
          atomicAdd(&s_sq[col], lq);
        }
      }
    }
    int nt = tile + 512;
    if (nt < 3200)
      issue_a64(A, nt * 64 + wid * 16, lane, &abuf[wid][i & 1][0]);
  }
  if (STATS) {
    __syncthreads();
    if (tid < 200) {
      atomicAdd(&stats[tid], s_sum[tid]);
      atomicAdd(&stats[200 + tid], s_sq[tid]);
    }
  }
}

// Persistent fused W3+W4: 4 row-tiles per block, A double-buffered in regs.
// xcls = leaky(leaky(X3@W3+b3)@W4+b4) as bf16 (1024x1600).
__global__ __launch_bounds__(256, 2) void gemm_w34_k(
    const unsigned short* __restrict__ A, const unsigned short* __restrict__ W3f,
    const unsigned short* __restrict__ W4f, const float* __restrict__ b3,
    const float* __restrict__ b4, unsigned short* __restrict__ xcls) {
  __shared__ unsigned short w3lds[7 * 4 * 64 * 8];   // 28 KB
  __shared__ unsigned short w4lds[2 * 64 * 8];       // 2 KB
  __shared__ unsigned short h3buf[128][72];          // 18 KB
  int tid = threadIdx.x;
  int lane = tid & 63;
  int wid = tid >> 6;

  for (int g0 = wid * 64; g0 < 1792; g0 += 256)
    gload_lds16(W3f + (size_t)(g0 + lane) * 8, &w3lds[(size_t)g0 * 8]);
  for (int g0 = wid * 64; g0 < 128; g0 += 256)
    gload_lds16(W4f + (size_t)(g0 + lane) * 8, &w4lds[(size_t)g0 * 8]);

  const unsigned short* baseA = A + (size_t)(lane & 15) * 200 + ((lane >> 4) << 3);
  int r0 = (lane >> 4) * 4;

  short8 aA0[7], aB0[7], aA1[7], aB1[7];
  {
    size_t off = (size_t)(blockIdx.x * 128 + wid * 32) * 200;
    aburst7(baseA + off, baseA + off + 16 * 200, aA0, aB0);
  }
  __builtin_amdgcn_sched_barrier(0);
  __syncthreads();

  #pragma unroll
  for (int t = 0; t < 4; ++t) {
    int rt = blockIdx.x + 400 * t;
    int row0 = rt * 128 + wid * 32;
    if (t < 3) {
      size_t off = (size_t)((rt + 400) * 128 + wid * 32) * 200;
      if (t & 1) aburst7(baseA + off, baseA + off + 16 * 200, aA0, aB0);
      else       aburst7(baseA + off, baseA + off + 16 * 200, aA1, aB1);
      __builtin_amdgcn_sched_barrier(0);
    }
    f32x4 accA[4], accB[4];
    #pragma unroll
    for (int f = 0; f < 4; ++f) { accA[f] = 0.0f; accB[f] = 0.0f; }
    #pragma unroll
    for (int ks = 0; ks < 7; ++ks) {
      const short8* wp = (const short8*)w3lds + (size_t)(ks * 4) * 64 + lane;
      short8 av = (t & 1) ? aA1[ks] : aA0[ks];
      short8 bv = (t & 1) ? aB1[ks] : aB0[ks];
      #pragma unroll
      for (int f = 0; f < 4; ++f) {
        short8 wv = wp[(size_t)f * 64];
        accA[f] = __builtin_amdgcn_mfma_f32_16x16x32_bf16(av, wv, accA[f], 0, 0, 0);
        accB[f] = __builtin_amdgcn_mfma_f32_16x16x32_bf16(bv, wv, accB[f], 0, 0, 0);
      }
    }
    #pragma unroll
    for (int f = 0; f < 4; ++f) {
      int col = f * 16 + (lane & 15);
      float bb = b3[col];
      #pragma unroll
      for (int r = 0; r < 4; ++r) {
        float v = accA[f][r] + bb;
        v = (v >= 0.f) ? v : 0.2f * v;
        h3buf[wid * 32 + r0 + r][col] = f2bf_rn(v);
        v = accB[f][r] + bb;
        v = (v >= 0.f) ? v : 0.2f * v;
        h3buf[wid * 32 + 16 + r0 + r][col] = f2bf_rn(v);
      }
    }
    // wave-local LDS write->read: compiler inserts lgkmcnt; no barrier needed.
    f32x4 acc2A = 0.0f, acc2B = 0.0f;
    #pragma unroll
    for (int ks = 0; ks < 2; ++ks) {
      short8 a2A = *(const short8*)&h3buf[wid * 32 + (lane & 15)][ks * 32 + ((lane >> 4) << 3)];
      short8 a2B = *(const short8*)&h3buf[wid * 32 + 16 + (lane & 15)][ks * 32 + ((lane >> 4) << 3)];
      short8 wv = *(const short8*)&w4lds[(size_t)(ks * 64 + lane) * 8];
      acc2A = __builtin_amdgcn_mfma_f32_16x16x32_bf16(a2A, wv, acc2A, 0, 0, 0);
      acc2B = __builtin_amdgcn_mfma_f32_16x16x32_bf16(a2B, wv, acc2B, 0, 0, 0);
    }
    int col = lane & 15;
    if (col < 8) {
      float bb = b4[col];
      #pragma unroll
      for (int r = 0; r < 4; ++r) {
        int row = row0 + r0 + r;
        float v = acc2A[r] + bb;
        v = (v >= 0.f) ? v : 0.2f * v;
        xcls[(size_t)(row / 200) * 1600 + (row % 200) * 8 + col] = f2bf_rn(v);
        int row2 = row + 16;
        v = acc2B[r] + bb;
        v = (v >= 0.f) ? v : 0.2f * v;
        xcls[(size_t)(row2 / 200) * 1600 + (row2 % 200) * 8 + col] = f2bf_rn(v);
      }
    }
  }
}

__global__ __launch_bounds__(256) void bn_scale_k(const float* __restrict__ stats,
                                                  const float* __restrict__ g,
                                                  const float* __restrict__ be,
                                                  float invN,
                                                  float* __restrict__ ss) {
  int c = threadIdx.x;
  if (c >= 200) return;
  float m = stats[c] * invN;
  float var = stats[200 + c] * invN - m * m;
  float sc = rsqrtf(var + 1e-5f) * g[c];
  ss[c] = sc;
  ss[200 + c] = be[c] - m * sc;
}

// bn3d stats over bf16 xcls (1024 x 1600; r = col>>3)
__global__ __launch_bounds__(256) void bn3d_stats_bf_k(const unsigned short* __restrict__ x,
                                                       float* __restrict__ stats) {
  int t = threadIdx.x;
  if (t >= 200) return;
  const unsigned short* p = x + (size_t)blockIdx.x * 16 * 1600 + t * 8;
  float s = 0.f, q = 0.f;
  for (int b = 0; b < 16; ++b) {
    const unsigned* u = (const unsigned*)(p + (size_t)b * 1600);
    #pragma unroll
    for (int i = 0; i < 4; ++i) {
      unsigned w = u[i];
      float v0 = __uint_as_float(w << 16);
      float v1 = __uint_as_float(w & 0xFFFF0000u);
      s += v0 + v1;
      q += v0 * v0 + v1 * v1;
    }
  }
  atomicAdd(&stats[t], s);
  atomicAdd(&stats[200 + t], q);
}

// Wc1 fold + fragment-major bf16 conversion: Wc1'[k][n] = Wc1[k][n]*sc[k>>3].
__global__ __launch_bounds__(256) void wcls_conv_k(const float* __restrict__ Wc1,
                                                   const float* __restrict__ ss,
                                                   unsigned short* __restrict__ dst) {
  int idx = blockIdx.x * 256 + threadIdx.x;
  if (idx >= 409600) return;
  int j = idx & 7;
  int lane = (idx >> 3) & 63;
  int rest = idx >> 9;
  int frag = rest & 3;
  int rest2 = rest >> 2;
  int ks = rest2 % 10;
  int slice = rest2 / 10;
  int kc = slice % 5, cb = slice / 5;
  int k = kc * 320 + ks * 32 + ((lane >> 4) << 3) + j;
  int col = cb * 64 + frag * 16 + (lane & 15);
  dst[idx] = f2bf_rn(Wc1[(size_t)k * 256 + col] * ss[k >> 3]);
}

// bias1' = bc1 + sum_k sh[k>>3] * Wc1[k][n]
__global__ __launch_bounds__(256) void bias1_init_k(const float* __restrict__ bc1,
                                                    float* __restrict__ bias1p) {
  bias1p[threadIdx.x] = bc1[threadIdx.x];
}
__global__ __launch_bounds__(256) void bias1_acc_k(const float* __restrict__ Wc1,
                                                   const float* __restrict__ ss,
                                                   float* __restrict__ bias1p) {
  int t = threadIdx.x;
  int k0 = blockIdx.x * 100;
  float a = 0.f;
  #pragma unroll 4
  for (int k = k0; k < k0 + 100; ++k)
    a += ss[200 + (k >> 3)] * Wc1[(size_t)k * 256 + t];
  atomicAdd(&bias1p[t], a);
}

// Classifier GEMM1 (MFMA, K-split): h1f += xcls[128 rows] @ Wc1' chunk.
__global__ __launch_bounds__(256, 3) void gemm_cls1_k(
    const unsigned short* __restrict__ xcls, const unsigned short* __restrict__ Wf,
    float* __restrict__ h1f) {
  __shared__ unsigned short wlds[10 * 4 * 64 * 8];  // 40 KB
  int tid = threadIdx.x;
  int lane = tid & 63;
  int wid = tid >> 6;
  const unsigned short* wsrc = Wf + (size_t)(blockIdx.y * 5 + blockIdx.z) * (10 * 4 * 64) * 8;
  for (int g0 = wid * 64; g0 < 2560; g0 += 256)
    gload_lds16(wsrc + (size_t)(g0 + lane) * 8, &wlds[(size_t)g0 * 8]);

  int row0 = blockIdx.x * 128 + wid * 32;
  int kbase = blockIdx.z * 320;
  const unsigned short* pA = xcls + (size_t)(row0 + (lane & 15)) * 1600 + kbase + ((lane >> 4) << 3);
  const unsigned short* pB = pA + 16 * 1600;
  short8 aA[10], aB[10];
  #pragma unroll
  for (int i = 0; i < 10; ++i) {
    aA[i] = *(const short8*)(pA + i * 32);
    aB[i] = *(const short8*)(pB + i * 32);
  }
  __builtin_amdgcn_sched_barrier(0);
  __syncthreads();

  f32x4 accA[4], accB[4];
  #pragma unroll
  for (int f = 0; f < 4; ++f) { accA[f] = 0.0f; accB[f] = 0.0f; }
  #pragma unroll
  for (int ks = 0; ks < 10; ++ks) {
    const short8* wp = (const short8*)wlds + (size_t)(ks * 4) * 64 + lane;
    #pragma unroll
    for (int f = 0; f < 4; ++f) {
      short8 wv = wp[(size_t)f * 64];
      accA[f] = __builtin_amdgcn_mfma_f32_16x16x32_bf16(aA[ks], wv, accA[f], 0, 0, 0);
      accB[f] = __builtin_amdgcn_mfma_f32_16x16x32_bf16(aB[ks], wv, accB[f], 0, 0, 0);
    }
  }
  int colbase = blockIdx.y * 64;
  int r0 = (lane >> 4) * 4;
  #pragma unroll
  for (int f = 0; f < 4; ++f) {
    int col = colbase + f * 16 + (lane & 15);
    #pragma unroll
    for (int r = 0; r < 4; ++r) {
      atomicAdd(&h1f[(size_t)(row0 + r0 + r) * 256 + col], accA[f][r]);
      atomicAdd(&h1f[(size_t)(row0 + 16 + r0 + r) * 256 + col], accB[f][r]);
    }
  }
}

// Classifier tail: h1 = leaky(h1f + bias1'), h2 = leaky(h1@Wc2+bc2), out = h2@Wc3+bc3.
__global__ __launch_bounds__(256) void classifier2_k(
    const float* __restrict__ h1f, const float* __restrict__ bias1p,
    const float* __restrict__ Wc2, const float* __restrict__ bc2,
    const float* __restrict__ Wc3, const float* __restrict__ bc3,
    float* __restrict__ out) {
  __shared__ float h1s[8][256];
  __shared__ float h2s[8][32];
  int t = threadIdx.x;
  int b0 = blockIdx.x * 8;
  #pragma unroll
  for (int j = 0; j < 8; ++j) {
    float v = h1f[(size_t)(b0 + j) * 256 + t] + bias1p[t];
    h1s[j][t] = (v >= 0.f) ? v : 0.2f * v;
  }
  __syncthreads();
  {
    int j = t >> 5, c = t & 31;
    float a = 0.f;
    #pragma unroll 8
    for (int k = 0; k < 256; ++k) a += h1s[j][k] * Wc2[k * 32 + c];
    float v = a + bc2[c];
    h2s[j][c] = (v >= 0.f) ? v : 0.2f * v;
  }
  __syncthreads();
  if (t < 16) {
    int j = t >> 1, c = t & 1;
    float a = 0.f;
    #pragma unroll
    for (int k = 0; k < 32; ++k) a += h2s[j][k] * Wc3[k * 2 + c];
    out[(size_t)(b0 + j) * 2 + c] = a + bc3[c];
  }
}

extern "C" void kernel_launch(void* const* d_in, const int* in_sizes, int n_in,
                              void* d_out, int out_size, void* d_ws, size_t ws_size,
                              hipStream_t stream) {
  const float* intra = (const float*)d_in[1];
  const float* inter = (const float*)d_in[2];
  const float* nodef = (const float*)d_in[3];
  const float* W0 = (const float*)d_in[4];
  const float* b0 = (const float*)d_in[5];
  const float* W1 = (const float*)d_in[6];
  const float* b1 = (const float*)d_in[7];
  const float* g1 = (const float*)d_in[8];
  const float* be1 = (const float*)d_in[9];
  const float* W2 = (const float*)d_in[10];
  const float* b2 = (const float*)d_in[11];
  const float* g2 = (const float*)d_in[12];
  const float* be2 = (const float*)d_in[13];
  const float* W3 = (const float*)d_in[14];
  const float* b3 = (const float*)d_in[15];
  const float* W4 = (const float*)d_in[16];
  const float* b4 = (const float*)d_in[17];
  const float* g3 = (const float*)d_in[18];
  const float* be3 = (const float*)d_in[19];
  const float* Wc1 = (const float*)d_in[20];
  const float* bc1 = (const float*)d_in[21];
  const float* Wc2 = (const float*)d_in[22];
  const float* bc2 = (const float*)d_in[23];
  const float* Wc3 = (const float*)d_in[24];
  const float* bc3 = (const float*)d_in[25];
  float* out = (float*)d_out;

  // Layout: 2 bf16 planes (ping-pong), then fp32 scratch + weights.
  unsigned short* P0 = (unsigned short*)d_ws;
  unsigned short* P1 = P0 + PLSZ;
  float* fbase = (float*)(P1 + PLSZ);
  float* rsI  = fbase;                         // 204,800
  float* rsP  = rsI + NROWS;                   // 8,192
  float* stats = rsP + BDIM * 8;               // 512
  float* ssbuf = stats + 512;                  // 512
  float* h1f  = ssbuf + 512;                   // 262,144
  float* bias1p = h1f + (size_t)BDIM * 256;    // 256 (pad 512)
  unsigned short* wt = (unsigned short*)(bias1p + 512);
  const size_t W13SZ = (size_t)G13 * 8;        // 46,592 shorts
  const size_t W3SZ  = 1 * 7 * 4 * 64 * 8;     // 14,336 shorts
  const size_t W4SZ  = 1 * 2 * 1 * 64 * 8;     // 1,024 shorts
  unsigned short* w0f = wt;
  unsigned short* w1f = w0f + W13SZ;
  unsigned short* w2f = w1f + W13SZ;
  unsigned short* w3f = w2f + W13SZ;
  unsigned short* w4f = w3f + W3SZ;
  unsigned short* wc1f = w4f + W4SZ;
  // xcls (1024x1600 bf16) aliases the (dead-at-that-point) P0 plane
  unsigned short* xcls = P0;

  // zero plane tail pads
  hipMemsetAsync(P0 + XELEMS, 0, PLPAD * 2, stream);
  hipMemsetAsync(P1 + XELEMS, 0, PLPAD * 2, stream);

  wconv3_k<<<(int)((W13SZ + 255) / 256), 256, 0, stream>>>(W0, 200, 200, 13, 1, 7, w0f);
  wconv3_k<<<(int)((W13SZ + 255) / 256), 256, 0, stream>>>(W1, 200, 200, 13, 1, 7, w1f);
  wconv3_k<<<(int)((W13SZ + 255) / 256), 256, 0, stream>>>(W2, 200, 200, 13, 1, 7, w2f);
  wconv3_k<<<(int)((W3SZ + 255) / 256), 256, 0, stream>>>(W3, 200, 64, 4, 1, 7, w3f);
  wconv3_k<<<(int)((W4SZ + 255) / 256), 256, 0, stream>>>(W4, 64, 8, 1, 1, 2, w4f);

  rowsum4_k<<<NROWS / 4, 256, 0, stream>>>(intra, rsI);
  intersum_k<<<(BDIM * 8 + 255) / 256, 256, 0, stream>>>(inter, rsP);

  // block 1: nodef (fp32) -> X1 (P0)
  seg_combine_bf_k<0, 0><<<BDIM, 128, 0, stream>>>(
      nodef, nullptr, rsI, rsP, nullptr, P0);

  // H = leaky(X1@W0+b0): P0 -> P1
  gemm_bf2_k<1, 0><<<256, 256, 0, stream>>>(P0, w0f, b0, P1, nullptr);
  // Y1 = H@W1+b1 (+stats): P1 -> P0
  hipMemsetAsync(stats, 0, 400 * sizeof(float), stream);
  gemm_bf2_k<0, 1><<<256, 256, 0, stream>>>(P1, w1f, b1, P0, stats);
  bn_scale_k<<<1, 256, 0, stream>>>(stats, g1, be1, 1.f / (float)NROWS, ssbuf);

  // block 2 (BN1 fold): P0 -> X2 (P1)
  seg_combine_bf_k<1, 1><<<BDIM, 128, 0, stream>>>(
      nullptr, P0, rsI, rsP, ssbuf, P1);

  // Y2 = leaky(X2@W2+b2) (+stats): P1 -> P0
  hipMemsetAsync(stats, 0, 400 * sizeof(float), stream);
  gemm_bf2_k<1, 1><<<256, 256, 0, stream>>>(P1, w2f, b2, P0, stats);
  bn_scale_k<<<1, 256, 0, stream>>>(stats, g2, be2, 1.f / (float)NROWS, ssbuf);

  // block 3 (BN2 fold): P0 -> X3 (P1)
  seg_combine_bf_k<1, 1><<<BDIM, 128, 0, stream>>>(
      nullptr, P0, rsI, rsP, ssbuf, P1);

  // xcls = leaky(leaky(X3@W3+b3)@W4+b4): P1 -> xcls (aliases P0, dead)
  gemm_w34_k<<<400, 256, 0, stream>>>(P1, w3f, w4f, b3, b4, xcls);

  // bn3d stats on xcls; affine folded into Wc1/bias1
  hipMemsetAsync(stats, 0, 400 * sizeof(float), stream);
  bn3d_stats_bf_k<<<64, 256, 0, stream>>>(xcls, stats);
  bn_scale_k<<<1, 256, 0, stream>>>(stats, g3, be3, 1.f / 8192.f, ssbuf);

  // fold BN3d into Wc1 (scale) and bias1 (shift)
  wcls_conv_k<<<1600, 256, 0, stream>>>(Wc1, ssbuf, wc1f);
  bias1_init_k<<<1, 256, 0, stream>>>(bc1, bias1p);
  bias1_acc_k<<<16, 256, 0, stream>>>(Wc1, ssbuf, bias1p);

  // classifier GEMM1 (MFMA, K-split atomics) then tail
  hipMemsetAsync(h1f, 0, (size_t)BDIM * 256 * sizeof(float), stream);
  gemm_cls1_k<<<dim3(8, 4, 5), 256, 0, stream>>>(xcls, wc1f, h1f);
  classifier2_k<<<BDIM / 8, 256, 0, stream>>>(h1f, bias1p, Wc2, bc2, Wc3, bc3, out);
}

// Round 16
// 429.356 us; speedup vs baseline: 1.5441x; 1.5441x over previous
//
#include <hip/hip_runtime.h>
#include <hip/hip_bf16.h>

// Problem constants
#define BDIM 1024
#define ROI 200
#define DIN 200
#define NSUB 8
#define NROWS (BDIM * ROI)           // 204800
#define XELEMS ((size_t)NROWS * 200) // 40,960,000
#define PLPAD 32                     // tail pad (shorts) per plane
#define PLSZ (XELEMS + PLPAD)        // shorts per bf16 plane

typedef __attribute__((ext_vector_type(8))) short short8;
typedef __attribute__((ext_vector_type(4))) float f32x4;

__device__ __constant__ float d_invcnt[8] = {
    1.f/41.f, 1.f/29.f, 1.f/21.f, 1.f/19.f, 1.f/20.f, 1.f/7.f, 1.f/21.f, 1.f/42.f};

__device__ inline unsigned short f2bf_rn(float x) {
  unsigned u = __float_as_uint(x);
  return (unsigned short)((u + 0x7FFFu + ((u >> 16) & 1u)) >> 16);
}
__device__ constexpr int seg_of_c(int r) {
  return (r < 41) ? 0 : (r < 70) ? 1 : (r < 91) ? 2 : (r < 110) ? 3
       : (r < 130) ? 4 : (r < 137) ? 5 : (r < 158) ? 6 : 7;
}

// async global->LDS, 16B per lane; LDS dest = wave-uniform base + lane*16
__device__ inline void gload_lds16(const unsigned short* src, unsigned short* dst) {
  __builtin_amdgcn_global_load_lds(
      (const __attribute__((address_space(1))) void*)src,
      (__attribute__((address_space(3))) void*)dst, 16, 0, 0);
}

// A-burst: whole K strip (7 granules) for two 16-row fragments (for w34)
__device__ inline void aburst7(const unsigned short* pA, const unsigned short* pB,
                               short8 (&aA)[7], short8 (&aB)[7]) {
  #pragma unroll
  for (int i = 0; i < 7; ++i) {
    aA[i] = *(const short8*)(pA + i * 32);
    aB[i] = *(const short8*)(pB + i * 32);
  }
}

// rs_intra: one wave per row, 4 rows per block
__global__ __launch_bounds__(256) void rowsum4_k(const float* __restrict__ in,
                                                 float* __restrict__ out) {
  int row = blockIdx.x * 4 + (threadIdx.x >> 6);
  int lane = threadIdx.x & 63;
  const float* p = in + (size_t)row * 200;
  float v = p[lane] + p[lane + 64] + p[lane + 128];
  if (lane < 8) v += p[lane + 192];
  #pragma unroll
  for (int off = 32; off > 0; off >>= 1) v += __shfl_down(v, off);
  if (lane == 0) out[row] = v;
}

__global__ __launch_bounds__(256) void intersum_k(const float* __restrict__ in,
                                                  float* __restrict__ out) {
  int i = blockIdx.x * blockDim.x + threadIdx.x;
  if (i >= BDIM * NSUB) return;
  const float* p = in + (size_t)i * 8;
  float v = 0.f;
  #pragma unroll
  for (int c = 0; c < 8; ++c) v += p[c];
  out[i] = v;
}

// Fused seg_mean + block_combine (+ optional BN fold), r-major full unroll.
template<int INPL, int BN>
__global__ __launch_bounds__(128) void seg_combine_bf_k(
    const float* __restrict__ xf, const unsigned short* __restrict__ xp,
    const float* __restrict__ rsI, const float* __restrict__ rsP,
    const float* __restrict__ ss, unsigned short* __restrict__ yp) {
  int b = blockIdx.x;
  int t = threadIdx.x;
  if (t >= 100) return;
  int c0 = 2 * t;
  size_t base = (size_t)b * 40000 + c0;
  float sc0 = 1.f, sh0 = 0.f, sc1 = 1.f, sh1 = 0.f;
  if (BN) { sc0 = ss[c0]; sh0 = ss[200 + c0]; sc1 = ss[c0 + 1]; sh1 = ss[200 + c0 + 1]; }
  float a0[8] = {0,0,0,0,0,0,0,0};
  float a1[8] = {0,0,0,0,0,0,0,0};
  #pragma unroll
  for (int r = 0; r < 200; ++r) {
    size_t idx = base + (size_t)r * 200;
    float v0, v1;
    if (INPL) {
      unsigned u = *(const unsigned*)(xp + idx);
      v0 = __uint_as_float(u << 16);
      v1 = __uint_as_float(u & 0xFFFF0000u);
    } else {
      float2 fv = *(const float2*)(xf + idx);
      v0 = fv.x; v1 = fv.y;
    }
    int s = seg_of_c(r);
    a0[s] += v0; a1[s] += v1;
  }
  float pr0[8], pr1[8];
  #pragma unroll
  for (int s = 0; s < 8; ++s) {
    float m0 = a0[s] * d_invcnt[s];
    float m1 = a1[s] * d_invcnt[s];
    if (BN) { m0 = m0 * sc0 + sh0; m1 = m1 * sc1 + sh1; }
    float rp = rsP[b * 8 + s];
    pr0[s] = rp * m0; pr1[s] = rp * m1;
  }
  const float* rsIb = rsI + b * 200;
  #pragma unroll
  for (int r = 0; r < 200; ++r) {
    size_t idx = base + (size_t)r * 200;
    float v0, v1;
    if (INPL) {
      unsigned u = *(const unsigned*)(xp + idx);
      v0 = __uint_as_float(u << 16);
      v1 = __uint_as_float(u & 0xFFFF0000u);
    } else {
      float2 fv = *(const float2*)(xf + idx);
      v0 = fv.x; v1 = fv.y;
    }
    if (BN) { v0 = v0 * sc0 + sh0; v1 = v1 * sc1 + sh1; }
    int s = seg_of_c(r);
    float ri = rsIb[r];
    float y0 = 0.5f * (ri * v0 + pr0[s]);
    float y1 = 0.5f * (ri * v1 + pr1[s]);
    unsigned o = (unsigned)f2bf_rn(y0) | ((unsigned)f2bf_rn(y1) << 16);
    *(unsigned*)(yp + idx) = o;
  }
}

// Weight preconversion into per-colblock fragment-major granule layout.
__global__ __launch_bounds__(256) void wconv3_k(const float* __restrict__ W, int K, int N,
                                                int NFRAG, int NB, int KSTEPS,
                                                unsigned short* __restrict__ dst) {
  int total = NB * KSTEPS * NFRAG * 64 * 8;
  int idx = blockIdx.x * 256 + threadIdx.x;
  if (idx >= total) return;
  int j = idx & 7;
  int lane = (idx >> 3) & 63;
  int rest = idx >> 9;
  int frag = rest % NFRAG;
  int rest2 = rest / NFRAG;
  int ks = rest2 % KSTEPS;
  int cb = rest2 / KSTEPS;
  int k = ks * 32 + ((lane >> 4) << 3) + j;
  int col = cb * NFRAG * 16 + frag * 16 + (lane & 15);
  float v = (k < K && col < N) ? W[(size_t)k * N + col] : 0.f;
  dst[idx] = f2bf_rn(v);
}

// Barrier-free per-wave async-LDS streaming GEMM.
// 512 thr = 8 waves; per wave: 16-row tiles (packed 6.4KB, contiguous),
// double-buffered in LDS via global_load_lds; counted s_waitcnt vmcnt(35)
// (= 28 stores + 7 loads issued after my buffer's loads, in-order retire).
// W col-slice (NFRAG=7, 50KB) resident. grid (128, 2). No loop barriers.
template<int ACT, int STATS>
__global__ __launch_bounds__(512, 1) void gemm_bf3_k(
    const unsigned short* __restrict__ A, const unsigned short* __restrict__ Wf,
    const float* __restrict__ bias, unsigned short* __restrict__ Cp,
    float* __restrict__ stats) {
  constexpr int G = 7 * 7 * 64;                  // 3136 granules (one col-slice)
  __shared__ unsigned short wlds[G * 8];         // 50,176 B
  __shared__ unsigned short abuf[8][2][400 * 8]; // 102,400 B
  __shared__ float s_sum[112];
  __shared__ float s_sq[112];
  int tid = threadIdx.x;
  int lane = tid & 63;
  int wid = tid >> 6;
  int cb = blockIdx.y;

  const unsigned short* wsrc = Wf + (size_t)cb * G * 8;
  for (int g0 = wid * 64; g0 < G; g0 += 512)
    gload_lds16(wsrc + (size_t)(g0 + lane) * 8, &wlds[(size_t)g0 * 8]);
  if (STATS && tid < 112) { s_sum[tid] = 0.f; s_sq[tid] = 0.f; }

  int gw = blockIdx.x * 8 + wid;   // 0..1023
  const int stride = 1024, nt = 12800;
  int row = lane & 15;
  int laneg = lane >> 4;

  // tile t: rows t*16..t*16+15, packed: src = A + t*3200 + slot*8, slot<400
  auto issue_tile = [&](int t, unsigned short* buf) {
    const unsigned short* src = A + (size_t)t * 3200;
    #pragma unroll
    for (int j = 0; j < 7; ++j) {
      int slot = j * 64 + lane;
      if (slot < 400)
        gload_lds16(src + (size_t)slot * 8, buf + (size_t)j * 512);
    }
  };

  issue_tile(gw, &abuf[wid][0][0]);
  issue_tile(gw + stride, &abuf[wid][1][0]);
  __syncthreads();  // W + both initial tiles resident (one-time full drain)

  float lsum[7], lsq[7];
  #pragma unroll
  for (int f = 0; f < 7; ++f) { lsum[f] = 0.f; lsq[f] = 0.f; }
  int colbase = cb * 112;

  for (int i = 0; ; ++i) {
    int t = gw + i * stride;
    if (t >= nt) break;
    if (i) {
      asm volatile("s_waitcnt vmcnt(35)" ::: "memory");
      __builtin_amdgcn_sched_barrier(0);
    }
    const unsigned short* ab = &abuf[wid][i & 1][0];
    f32x4 acc[7];
    #pragma unroll
    for (int f = 0; f < 7; ++f) acc[f] = 0.0f;
    #pragma unroll
    for (int ks = 0; ks < 7; ++ks) {
      int cs = ks * 4 + laneg;
      if (cs > 24) cs = 0;  // k>=200 lane: W slice is zero there
      short8 av = *(const short8*)&ab[(size_t)(row * 25 + cs) * 8];
      const short8* wp = (const short8*)wlds + (size_t)(ks * 7) * 64 + lane;
      #pragma unroll
      for (int f = 0; f < 7; ++f) {
        short8 wv = wp[(size_t)f * 64];
        acc[f] = __builtin_amdgcn_mfma_f32_16x16x32_bf16(av, wv, acc[f], 0, 0, 0);
      }
    }
    // ensure all ds_reads sampled before DMA into this buffer is re-issued
    asm volatile("s_waitcnt lgkmcnt(0)" ::: "memory");
    __builtin_amdgcn_sched_barrier(0);
    // epilogue stores (28 per wave) BEFORE next load issue (vmcnt ordering)
    int row0 = t * 16 + laneg * 4;
    #pragma unroll
    for (int f = 0; f < 7; ++f) {
      int col = colbase + f * 16 + row;
      if (col < 200) {
        float b = bias[col];
        #pragma unroll
        for (int r = 0; r < 4; ++r) {
          float v = acc[f][r] + b;
          if (ACT) v = (v >= 0.f) ? v : 0.2f * v;
          Cp[(size_t)(row0 + r) * 200 + col] = f2bf_rn(v);
          if (STATS) { lsum[f] += v; lsq[f] += v * v; }
        }
      }
    }
    __builtin_amdgcn_sched_barrier(0);
    int t2 = t + 2 * stride;
    issue_tile(t2 < nt ? t2 : gw, &abuf[wid][i & 1][0]);
    __builtin_amdgcn_sched_barrier(0);
  }

  if (STATS) {
    #pragma unroll
    for (int f = 0; f < 7; ++f) {
      float s = lsum[f] + __shfl_xor(lsum[f], 16) ;
      s += __shfl_xor(s, 32);
      float q = lsq[f] + __shfl_xor(lsq[f], 16);
      q += __shfl_xor(q, 32);
      if (laneg == 0) {
        atomicAdd(&s_sum[f * 16 + row], s);
        atomicAdd(&s_sq[f * 16 + row], q);
      }
    }
    __syncthreads();
    if (tid < 112) {
      int col = colbase + tid;
      if (col < 200) {
        atomicAdd(&stats[col], s_sum[tid]);
        atomicAdd(&stats[200 + col], s_sq[tid]);
      }
    }
  }
}

// Persistent fused W3+W4: 4 row-tiles per block, A double-buffered in regs.
__global__ __launch_bounds__(256, 2) void gemm_w34_k(
    const unsigned short* __restrict__ A, const unsigned short* __restrict__ W3f,
    const unsigned short* __restrict__ W4f, const float* __restrict__ b3,
    const float* __restrict__ b4, unsigned short* __restrict__ xcls) {
  __shared__ unsigned short w3lds[7 * 4 * 64 * 8];   // 28 KB
  __shared__ unsigned short w4lds[2 * 64 * 8];       // 2 KB
  __shared__ unsigned short h3buf[128][72];          // 18 KB
  int tid = threadIdx.x;
  int lane = tid & 63;
  int wid = tid >> 6;

  for (int g0 = wid * 64; g0 < 1792; g0 += 256)
    gload_lds16(W3f + (size_t)(g0 + lane) * 8, &w3lds[(size_t)g0 * 8]);
  for (int g0 = wid * 64; g0 < 128; g0 += 256)
    gload_lds16(W4f + (size_t)(g0 + lane) * 8, &w4lds[(size_t)g0 * 8]);

  const unsigned short* baseA = A + (size_t)(lane & 15) * 200 + ((lane >> 4) << 3);
  int r0 = (lane >> 4) * 4;

  short8 aA0[7], aB0[7], aA1[7], aB1[7];
  {
    size_t off = (size_t)(blockIdx.x * 128 + wid * 32) * 200;
    aburst7(baseA + off, baseA + off + 16 * 200, aA0, aB0);
  }
  __builtin_amdgcn_sched_barrier(0);
  __syncthreads();

  #pragma unroll
  for (int t = 0; t < 4; ++t) {
    int rt = blockIdx.x + 400 * t;
    int row0 = rt * 128 + wid * 32;
    if (t < 3) {
      size_t off = (size_t)((rt + 400) * 128 + wid * 32) * 200;
      if (t & 1) aburst7(baseA + off, baseA + off + 16 * 200, aA0, aB0);
      else       aburst7(baseA + off, baseA + off + 16 * 200, aA1, aB1);
      __builtin_amdgcn_sched_barrier(0);
    }
    f32x4 accA[4], accB[4];
    #pragma unroll
    for (int f = 0; f < 4; ++f) { accA[f] = 0.0f; accB[f] = 0.0f; }
    #pragma unroll
    for (int ks = 0; ks < 7; ++ks) {
      const short8* wp = (const short8*)w3lds + (size_t)(ks * 4) * 64 + lane;
      short8 av = (t & 1) ? aA1[ks] : aA0[ks];
      short8 bv = (t & 1) ? aB1[ks] : aB0[ks];
      #pragma unroll
      for (int f = 0; f < 4; ++f) {
        short8 wv = wp[(size_t)f * 64];
        accA[f] = __builtin_amdgcn_mfma_f32_16x16x32_bf16(av, wv, accA[f], 0, 0, 0);
        accB[f] = __builtin_amdgcn_mfma_f32_16x16x32_bf16(bv, wv, accB[f], 0, 0, 0);
      }
    }
    #pragma unroll
    for (int f = 0; f < 4; ++f) {
      int col = f * 16 + (lane & 15);
      float bb = b3[col];
      #pragma unroll
      for (int r = 0; r < 4; ++r) {
        float v = accA[f][r] + bb;
        v = (v >= 0.f) ? v : 0.2f * v;
        h3buf[wid * 32 + r0 + r][col] = f2bf_rn(v);
        v = accB[f][r] + bb;
        v = (v >= 0.f) ? v : 0.2f * v;
        h3buf[wid * 32 + 16 + r0 + r][col] = f2bf_rn(v);
      }
    }
    // wave-local LDS write->read: compiler inserts lgkmcnt; no barrier needed.
    f32x4 acc2A = 0.0f, acc2B = 0.0f;
    #pragma unroll
    for (int ks = 0; ks < 2; ++ks) {
      short8 a2A = *(const short8*)&h3buf[wid * 32 + (lane & 15)][ks * 32 + ((lane >> 4) << 3)];
      short8 a2B = *(const short8*)&h3buf[wid * 32 + 16 + (lane & 15)][ks * 32 + ((lane >> 4) << 3)];
      short8 wv = *(const short8*)&w4lds[(size_t)(ks * 64 + lane) * 8];
      acc2A = __builtin_amdgcn_mfma_f32_16x16x32_bf16(a2A, wv, acc2A, 0, 0, 0);
      acc2B = __builtin_amdgcn_mfma_f32_16x16x32_bf16(a2B, wv, acc2B, 0, 0, 0);
    }
    int col = lane & 15;
    if (col < 8) {
      float bb = b4[col];
      #pragma unroll
      for (int r = 0; r < 4; ++r) {
        int row = row0 + r0 + r;
        float v = acc2A[r] + bb;
        v = (v >= 0.f) ? v : 0.2f * v;
        xcls[(size_t)(row / 200) * 1600 + (row % 200) * 8 + col] = f2bf_rn(v);
        int row2 = row + 16;
        v = acc2B[r] + bb;
        v = (v >= 0.f) ? v : 0.2f * v;
        xcls[(size_t)(row2 / 200) * 1600 + (row2 % 200) * 8 + col] = f2bf_rn(v);
      }
    }
  }
}

__global__ __launch_bounds__(256) void bn_scale_k(const float* __restrict__ stats,
                                                  const float* __restrict__ g,
                                                  const float* __restrict__ be,
                                                  float invN,
                                                  float* __restrict__ ss) {
  int c = threadIdx.x;
  if (c >= 200) return;
  float m = stats[c] * invN;
  float var = stats[200 + c] * invN - m * m;
  float sc = rsqrtf(var + 1e-5f) * g[c];
  ss[c] = sc;
  ss[200 + c] = be[c] - m * sc;
}

// bn3d stats over bf16 xcls (1024 x 1600; r = col>>3)
__global__ __launch_bounds__(256) void bn3d_stats_bf_k(const unsigned short* __restrict__ x,
                                                       float* __restrict__ stats) {
  int t = threadIdx.x;
  if (t >= 200) return;
  const unsigned short* p = x + (size_t)blockIdx.x * 16 * 1600 + t * 8;
  float s = 0.f, q = 0.f;
  for (int b = 0; b < 16; ++b) {
    const unsigned* u = (const unsigned*)(p + (size_t)b * 1600);
    #pragma unroll
    for (int i = 0; i < 4; ++i) {
      unsigned w = u[i];
      float v0 = __uint_as_float(w << 16);
      float v1 = __uint_as_float(w & 0xFFFF0000u);
      s += v0 + v1;
      q += v0 * v0 + v1 * v1;
    }
  }
  atomicAdd(&stats[t], s);
  atomicAdd(&stats[200 + t], q);
}

// Wc1 fold + fragment-major bf16 conversion: Wc1'[k][n] = Wc1[k][n]*sc[k>>3].
__global__ __launch_bounds__(256) void wcls_conv_k(const float* __restrict__ Wc1,
                                                   const float* __restrict__ ss,
                                                   unsigned short* __restrict__ dst) {
  int idx = blockIdx.x * 256 + threadIdx.x;
  if (idx >= 409600) return;
  int j = idx & 7;
  int lane = (idx >> 3) & 63;
  int rest = idx >> 9;
  int frag = rest & 3;
  int rest2 = rest >> 2;
  int ks = rest2 % 10;
  int slice = rest2 / 10;
  int kc = slice % 5, cb = slice / 5;
  int k = kc * 320 + ks * 32 + ((lane >> 4) << 3) + j;
  int col = cb * 64 + frag * 16 + (lane & 15);
  dst[idx] = f2bf_rn(Wc1[(size_t)k * 256 + col] * ss[k >> 3]);
}

// bias1' = bc1 + sum_k sh[k>>3] * Wc1[k][n]
__global__ __launch_bounds__(256) void bias1_init_k(const float* __restrict__ bc1,
                                                    float* __restrict__ bias1p) {
  bias1p[threadIdx.x] = bc1[threadIdx.x];
}
__global__ __launch_bounds__(256) void bias1_acc_k(const float* __restrict__ Wc1,
                                                   const float* __restrict__ ss,
                                                   float* __restrict__ bias1p) {
  int t = threadIdx.x;
  int k0 = blockIdx.x * 100;
  float a = 0.f;
  #pragma unroll 4
  for (int k = k0; k < k0 + 100; ++k)
    a += ss[200 + (k >> 3)] * Wc1[(size_t)k * 256 + t];
  atomicAdd(&bias1p[t], a);
}

// Classifier GEMM1 (MFMA, K-split): h1f += xcls[128 rows] @ Wc1' chunk.
__global__ __launch_bounds__(256, 3) void gemm_cls1_k(
    const unsigned short* __restrict__ xcls, const unsigned short* __restrict__ Wf,
    float* __restrict__ h1f) {
  __shared__ unsigned short wlds[10 * 4 * 64 * 8];  // 40 KB
  int tid = threadIdx.x;
  int lane = tid & 63;
  int wid = tid >> 6;
  const unsigned short* wsrc = Wf + (size_t)(blockIdx.y * 5 + blockIdx.z) * (10 * 4 * 64) * 8;
  for (int g0 = wid * 64; g0 < 2560; g0 += 256)
    gload_lds16(wsrc + (size_t)(g0 + lane) * 8, &wlds[(size_t)g0 * 8]);

  int row0 = blockIdx.x * 128 + wid * 32;
  int kbase = blockIdx.z * 320;
  const unsigned short* pA = xcls + (size_t)(row0 + (lane & 15)) * 1600 + kbase + ((lane >> 4) << 3);
  const unsigned short* pB = pA + 16 * 1600;
  short8 aA[10], aB[10];
  #pragma unroll
  for (int i = 0; i < 10; ++i) {
    aA[i] = *(const short8*)(pA + i * 32);
    aB[i] = *(const short8*)(pB + i * 32);
  }
  __builtin_amdgcn_sched_barrier(0);
  __syncthreads();

  f32x4 accA[4], accB[4];
  #pragma unroll
  for (int f = 0; f < 4; ++f) { accA[f] = 0.0f; accB[f] = 0.0f; }
  #pragma unroll
  for (int ks = 0; ks < 10; ++ks) {
    const short8* wp = (const short8*)wlds + (size_t)(ks * 4) * 64 + lane;
    #pragma unroll
    for (int f = 0; f < 4; ++f) {
      short8 wv = wp[(size_t)f * 64];
      accA[f] = __builtin_amdgcn_mfma_f32_16x16x32_bf16(aA[ks], wv, accA[f], 0, 0, 0);
      accB[f] = __builtin_amdgcn_mfma_f32_16x16x32_bf16(aB[ks], wv, accB[f], 0, 0, 0);
    }
  }
  int colbase = blockIdx.y * 64;
  int r0 = (lane >> 4) * 4;
  #pragma unroll
  for (int f = 0; f < 4; ++f) {
    int col = colbase + f * 16 + (lane & 15);
    #pragma unroll
    for (int r = 0; r < 4; ++r) {
      atomicAdd(&h1f[(size_t)(row0 + r0 + r) * 256 + col], accA[f][r]);
      atomicAdd(&h1f[(size_t)(row0 + 16 + r0 + r) * 256 + col], accB[f][r]);
    }
  }
}

// Classifier tail: h1 = leaky(h1f + bias1'), h2 = leaky(h1@Wc2+bc2), out = h2@Wc3+bc3.
__global__ __launch_bounds__(256) void classifier2_k(
    const float* __restrict__ h1f, const float* __restrict__ bias1p,
    const float* __restrict__ Wc2, const float* __restrict__ bc2,
    const float* __restrict__ Wc3, const float* __restrict__ bc3,
    float* __restrict__ out) {
  __shared__ float h1s[8][256];
  __shared__ float h2s[8][32];
  int t = threadIdx.x;
  int b0 = blockIdx.x * 8;
  #pragma unroll
  for (int j = 0; j < 8; ++j) {
    float v = h1f[(size_t)(b0 + j) * 256 + t] + bias1p[t];
    h1s[j][t] = (v >= 0.f) ? v : 0.2f * v;
  }
  __syncthreads();
  {
    int j = t >> 5, c = t & 31;
    float a = 0.f;
    #pragma unroll 8
    for (int k = 0; k < 256; ++k) a += h1s[j][k] * Wc2[k * 32 + c];
    float v = a + bc2[c];
    h2s[j][c] = (v >= 0.f) ? v : 0.2f * v;
  }
  __syncthreads();
  if (t < 16) {
    int j = t >> 1, c = t & 1;
    float a = 0.f;
    #pragma unroll
    for (int k = 0; k < 32; ++k) a += h2s[j][k] * Wc3[k * 2 + c];
    out[(size_t)(b0 + j) * 2 + c] = a + bc3[c];
  }
}

extern "C" void kernel_launch(void* const* d_in, const int* in_sizes, int n_in,
                              void* d_out, int out_size, void* d_ws, size_t ws_size,
                              hipStream_t stream) {
  const float* intra = (const float*)d_in[1];
  const float* inter = (const float*)d_in[2];
  const float* nodef = (const float*)d_in[3];
  const float* W0 = (const float*)d_in[4];
  const float* b0 = (const float*)d_in[5];
  const float* W1 = (const float*)d_in[6];
  const float* b1 = (const float*)d_in[7];
  const float* g1 = (const float*)d_in[8];
  const float* be1 = (const float*)d_in[9];
  const float* W2 = (const float*)d_in[10];
  const float* b2 = (const float*)d_in[11];
  const float* g2 = (const float*)d_in[12];
  const float* be2 = (const float*)d_in[13];
  const float* W3 = (const float*)d_in[14];
  const float* b3 = (const float*)d_in[15];
  const float* W4 = (const float*)d_in[16];
  const float* b4 = (const float*)d_in[17];
  const float* g3 = (const float*)d_in[18];
  const float* be3 = (const float*)d_in[19];
  const float* Wc1 = (const float*)d_in[20];
  const float* bc1 = (const float*)d_in[21];
  const float* Wc2 = (const float*)d_in[22];
  const float* bc2 = (const float*)d_in[23];
  const float* Wc3 = (const float*)d_in[24];
  const float* bc3 = (const float*)d_in[25];
  float* out = (float*)d_out;

  // Layout: 2 bf16 planes (ping-pong), then fp32 scratch + weights.
  unsigned short* P0 = (unsigned short*)d_ws;
  unsigned short* P1 = P0 + PLSZ;
  float* fbase = (float*)(P1 + PLSZ);
  float* rsI  = fbase;                         // 204,800
  float* rsP  = rsI + NROWS;                   // 8,192
  float* stats = rsP + BDIM * 8;               // 512
  float* ssbuf = stats + 512;                  // 512
  float* h1f  = ssbuf + 512;                   // 262,144
  float* bias1p = h1f + (size_t)BDIM * 256;    // 256 (pad 512)
  unsigned short* wt = (unsigned short*)(bias1p + 512);
  const size_t W200SZ = 2 * 7 * 7 * 64 * 8;    // 50,176 shorts
  const size_t W3SZ   = 1 * 7 * 4 * 64 * 8;    // 14,336 shorts
  const size_t W4SZ   = 1 * 2 * 1 * 64 * 8;    // 1,024 shorts
  unsigned short* w0f = wt;
  unsigned short* w1f = w0f + W200SZ;
  unsigned short* w2f = w1f + W200SZ;
  unsigned short* w3f = w2f + W200SZ;
  unsigned short* w4f = w3f + W3SZ;
  unsigned short* wc1f = w4f + W4SZ;
  // xcls (1024x1600 bf16) aliases the (dead-at-that-point) P0 plane
  unsigned short* xcls = P0;

  // zero plane tail pads
  hipMemsetAsync(P0 + XELEMS, 0, PLPAD * 2, stream);
  hipMemsetAsync(P1 + XELEMS, 0, PLPAD * 2, stream);

  wconv3_k<<<(int)((W200SZ + 255) / 256), 256, 0, stream>>>(W0, 200, 200, 7, 2, 7, w0f);
  wconv3_k<<<(int)((W200SZ + 255) / 256), 256, 0, stream>>>(W1, 200, 200, 7, 2, 7, w1f);
  wconv3_k<<<(int)((W200SZ + 255) / 256), 256, 0, stream>>>(W2, 200, 200, 7, 2, 7, w2f);
  wconv3_k<<<(int)((W3SZ + 255) / 256), 256, 0, stream>>>(W3, 200, 64, 4, 1, 7, w3f);
  wconv3_k<<<(int)((W4SZ + 255) / 256), 256, 0, stream>>>(W4, 64, 8, 1, 1, 2, w4f);

  rowsum4_k<<<NROWS / 4, 256, 0, stream>>>(intra, rsI);
  intersum_k<<<(BDIM * 8 + 255) / 256, 256, 0, stream>>>(inter, rsP);

  // block 1: nodef (fp32) -> X1 (P0)
  seg_combine_bf_k<0, 0><<<BDIM, 128, 0, stream>>>(
      nodef, nullptr, rsI, rsP, nullptr, P0);

  // H = leaky(X1@W0+b0): P0 -> P1
  gemm_bf3_k<1, 0><<<dim3(128, 2), 512, 0, stream>>>(P0, w0f, b0, P1, nullptr);
  // Y1 = H@W1+b1 (+stats): P1 -> P0
  hipMemsetAsync(stats, 0, 400 * sizeof(float), stream);
  gemm_bf3_k<0, 1><<<dim3(128, 2), 512, 0, stream>>>(P1, w1f, b1, P0, stats);
  bn_scale_k<<<1, 256, 0, stream>>>(stats, g1, be1, 1.f / (float)NROWS, ssbuf);

  // block 2 (BN1 fold): P0 -> X2 (P1)
  seg_combine_bf_k<1, 1><<<BDIM, 128, 0, stream>>>(
      nullptr, P0, rsI, rsP, ssbuf, P1);

  // Y2 = leaky(X2@W2+b2) (+stats): P1 -> P0
  hipMemsetAsync(stats, 0, 400 * sizeof(float), stream);
  gemm_bf3_k<1, 1><<<dim3(128, 2), 512, 0, stream>>>(P1, w2f, b2, P0, stats);
  bn_scale_k<<<1, 256, 0, stream>>>(stats, g2, be2, 1.f / (float)NROWS, ssbuf);

  // block 3 (BN2 fold): P0 -> X3 (P1)
  seg_combine_bf_k<1, 1><<<BDIM, 128, 0, stream>>>(
      nullptr, P0, rsI, rsP, ssbuf, P1);

  // xcls = leaky(leaky(X3@W3+b3)@W4+b4): P1 -> xcls (aliases P0, dead)
  gemm_w34_k<<<400, 256, 0, stream>>>(P1, w3f, w4f, b3, b4, xcls);

  // bn3d stats on xcls; affine folded into Wc1/bias1
  hipMemsetAsync(stats, 0, 400 * sizeof(float), stream);
  bn3d_stats_bf_k<<<64, 256, 0, stream>>>(xcls, stats);
  bn_scale_k<<<1, 256, 0, stream>>>(stats, g3, be3, 1.f / 8192.f, ssbuf);

  // fold BN3d into Wc1 (scale) and bias1 (shift)
  wcls_conv_k<<<1600, 256, 0, stream>>>(Wc1, ssbuf, wc1f);
  bias1_init_k<<<1, 256, 0, stream>>>(bc1, bias1p);
  bias1_acc_k<<<16, 256, 0, stream>>>(Wc1, ssbuf, bias1p);

  // classifier GEMM1 (MFMA, K-split atomics) then tail
  hipMemsetAsync(h1f, 0, (size_t)BDIM * 256 * sizeof(float), stream);
  gemm_cls1_k<<<dim3(8, 4, 5), 256, 0, stream>>>(xcls, wc1f, h1f);
  classifier2_k<<<BDIM / 8, 256, 0, stream>>>(h1f, bias1p, Wc2, bc2, Wc3, bc3, out);
}